// Round 1
// baseline (560.443 us; speedup 1.0000x reference)
//
#include <hip/hip_runtime.h>
#include <hip/hip_bf16.h>
#include <math.h>

typedef __bf16 bf16_t;
typedef __bf16 bf16x8 __attribute__((ext_vector_type(8)));
typedef __bf16 bf16x4 __attribute__((ext_vector_type(4)));
typedef float  f32x4  __attribute__((ext_vector_type(4)));

#define D 768

// ---------------- block reduction helpers (blockDim == 256) ----------------
__device__ inline double blk_sum(double x, double* s) {
#pragma unroll
  for (int m = 32; m; m >>= 1) x += __shfl_xor(x, m);
  __syncthreads();
  if ((threadIdx.x & 63) == 0) s[threadIdx.x >> 6] = x;
  __syncthreads();
  return s[0] + s[1] + s[2] + s[3];
}

__device__ inline double blk_max(double x, double* s) {
#pragma unroll
  for (int m = 32; m; m >>= 1) x = fmax(x, __shfl_xor(x, m));
  __syncthreads();
  if ((threadIdx.x & 63) == 0) s[threadIdx.x >> 6] = x;
  __syncthreads();
  return fmax(fmax(s[0], s[1]), fmax(s[2], s[3]));
}

// ---------------- K1: L2-normalize rows (f64-accumulated norm) -------------
// One wave per row (4 rows / 256-thread block). Pad rows -> zeros (bf16 out).
template <bool OUT_BF16>
__global__ __launch_bounds__(256) void norm_rows(const float* __restrict__ src,
                                                 void* __restrict__ dst,
                                                 int n_valid, int n_total) {
  int row  = blockIdx.x * 4 + (threadIdx.x >> 6);
  int lane = threadIdx.x & 63;
  if (row >= n_total) return;
  if (row >= n_valid) {
    if (OUT_BF16) {
      bf16_t* drow = (bf16_t*)dst + (size_t)row * D;
      bf16x4 z = {(bf16_t)0.f, (bf16_t)0.f, (bf16_t)0.f, (bf16_t)0.f};
#pragma unroll
      for (int j = 0; j < 3; j++) *(bf16x4*)(drow + 4 * (lane + 64 * j)) = z;
    }
    return;
  }
  const float4* s = (const float4*)(src + (size_t)row * D);
  float4 v[3];
  double ss = 0.0;
#pragma unroll
  for (int j = 0; j < 3; j++) {
    v[j] = s[lane + 64 * j];
    ss += (double)v[j].x * v[j].x + (double)v[j].y * v[j].y +
          (double)v[j].z * v[j].z + (double)v[j].w * v[j].w;
  }
#pragma unroll
  for (int m = 32; m; m >>= 1) ss += __shfl_xor(ss, m);
  double inv = 1.0 / fmax(sqrt(ss), 1e-12);
  if (OUT_BF16) {
    bf16_t* drow = (bf16_t*)dst + (size_t)row * D;
#pragma unroll
    for (int j = 0; j < 3; j++) {
      bf16x4 o;
      o[0] = (bf16_t)(float)((double)v[j].x * inv);
      o[1] = (bf16_t)(float)((double)v[j].y * inv);
      o[2] = (bf16_t)(float)((double)v[j].z * inv);
      o[3] = (bf16_t)(float)((double)v[j].w * inv);
      *(bf16x4*)(drow + 4 * (lane + 64 * j)) = o;
    }
  } else {
    float* drow = (float*)dst + (size_t)row * D;
#pragma unroll
    for (int j = 0; j < 3; j++) {
      float4 o;
      o.x = (float)((double)v[j].x * inv);
      o.y = (float)((double)v[j].y * inv);
      o.z = (float)((double)v[j].z * inv);
      o.w = (float)((double)v[j].w * inv);
      ((float4*)drow)[lane + 64 * j] = o;
    }
  }
}

// ---------------- K2: max-sim GEMM (bf16 MFMA, fused row-max) ---------------
// Block = 64 W-rows (4 waves x 16 rows, A held in registers), loops all U
// tiles of 16 prototypes; B tile double-buffered in LDS (row pad +8 bf16
// -> 2-way bank aliasing on ds_read_b128, which is free).
#define LDSROW 776  // 768 + 8 pad (bf16 units)

__global__ __launch_bounds__(256) void maxsim_gemm(const bf16_t* __restrict__ Wb,
                                                   const bf16_t* __restrict__ Tb,
                                                   float* __restrict__ maxsim,
                                                   int V, int U, int NT) {
  __shared__ __align__(16) bf16_t lds[2][16 * LDSROW];
  const int tid  = threadIdx.x;
  const int lane = tid & 63;
  const int rowbase = blockIdx.x * 64 + (tid >> 6) * 16;

  // A fragments: lane holds row (lane&15), k = (lane>>4)*8 + j within each k32 step
  bf16x8 a[24];
  const bf16_t* arow = Wb + (size_t)(rowbase + (lane & 15)) * D + ((lane >> 4) * 8);
#pragma unroll
  for (int kk = 0; kk < 24; kk++) a[kk] = *(const bf16x8*)(arow + kk * 32);

  auto stage = [&](int buf, int nt) {
    const ulonglong2* src = (const ulonglong2*)(Tb + (size_t)nt * 16 * D);
#pragma unroll
    for (int j = 0; j < 6; j++) {
      int c = tid + j * 256;        // 1536 x 16B chunks
      int r = c / 96, w = c % 96;   // 96 chunks per row
      *(ulonglong2*)&lds[buf][r * LDSROW + w * 8] = src[c];
    }
  };

  f32x4 mx = {-1e30f, -1e30f, -1e30f, -1e30f};
  stage(0, 0);
  for (int nt = 0; nt < NT; nt++) {
    __syncthreads();
    if (nt + 1 < NT) stage((nt + 1) & 1, nt + 1);
    f32x4 acc = {0.f, 0.f, 0.f, 0.f};
    const bf16_t* brow = &lds[nt & 1][(lane & 15) * LDSROW + ((lane >> 4) * 8)];
#pragma unroll
    for (int kk = 0; kk < 24; kk++) {
      bf16x8 b = *(const bf16x8*)(brow + kk * 32);
      acc = __builtin_amdgcn_mfma_f32_16x16x32_bf16(a[kk], b, acc, 0, 0, 0);
    }
    if (nt * 16 + (lane & 15) < U) {
#pragma unroll
      for (int j = 0; j < 4; j++) mx[j] = fmaxf(mx[j], acc[j]);
    }
  }
  // reduce across the 16 lanes of each row-group (C layout: col=lane&15,
  // row=(lane>>4)*4+j)
#pragma unroll
  for (int m = 1; m < 16; m <<= 1) {
#pragma unroll
    for (int j = 0; j < 4; j++) mx[j] = fmaxf(mx[j], __shfl_xor(mx[j], m));
  }
  if ((lane & 15) == 0) {
    int r0 = rowbase + (lane >> 4) * 4;
#pragma unroll
    for (int j = 0; j < 4; j++)
      if (r0 + j < V) maxsim[r0 + j] = mx[j];
  }
}

// ---------------- K4: sim_bq = ts_norm @ sup_norm^T, f64 accumulation ------
// 64x64 tile per block, 4x4 per thread, K-step 16, LDS holds f64 tiles.
__global__ __launch_bounds__(256) void sim_bq_gemm(const float* __restrict__ TSn,
                                                   const float* __restrict__ SUPn,
                                                   double* __restrict__ sim, int Q) {
  __shared__ double As[16][65];
  __shared__ double Bs[16][65];
  const int tid = threadIdx.x;
  const int tx = tid & 15, ty = tid >> 4;
  const int m0 = blockIdx.y * 64;
  const int q0 = blockIdx.x * 64;
  const int sr = tid >> 2;         // staging row 0..63
  const int sk = (tid & 3) * 4;    // staging k offset

  double acc[4][4] = {};
  for (int k0 = 0; k0 < D; k0 += 16) {
    __syncthreads();
    float4 av = *(const float4*)(TSn + (size_t)(m0 + sr) * D + k0 + sk);
    float4 bv = {0.f, 0.f, 0.f, 0.f};
    if (q0 + sr < Q) bv = *(const float4*)(SUPn + (size_t)(q0 + sr) * D + k0 + sk);
    As[sk + 0][sr] = av.x; As[sk + 1][sr] = av.y;
    As[sk + 2][sr] = av.z; As[sk + 3][sr] = av.w;
    Bs[sk + 0][sr] = bv.x; Bs[sk + 1][sr] = bv.y;
    Bs[sk + 2][sr] = bv.z; Bs[sk + 3][sr] = bv.w;
    __syncthreads();
#pragma unroll
    for (int k = 0; k < 16; k++) {
      double a0 = As[k][ty * 4 + 0], a1 = As[k][ty * 4 + 1];
      double a2 = As[k][ty * 4 + 2], a3 = As[k][ty * 4 + 3];
      double b0 = Bs[k][tx * 4 + 0], b1 = Bs[k][tx * 4 + 1];
      double b2 = Bs[k][tx * 4 + 2], b3 = Bs[k][tx * 4 + 3];
      acc[0][0] += a0 * b0; acc[0][1] += a0 * b1; acc[0][2] += a0 * b2; acc[0][3] += a0 * b3;
      acc[1][0] += a1 * b0; acc[1][1] += a1 * b1; acc[1][2] += a1 * b2; acc[1][3] += a1 * b3;
      acc[2][0] += a2 * b0; acc[2][1] += a2 * b1; acc[2][2] += a2 * b2; acc[2][3] += a2 * b3;
      acc[3][0] += a3 * b0; acc[3][1] += a3 * b1; acc[3][2] += a3 * b2; acc[3][3] += a3 * b3;
    }
  }
#pragma unroll
  for (int i = 0; i < 4; i++)
#pragma unroll
    for (int j = 0; j < 4; j++) {
      int q = q0 + tx * 4 + j;
      if (q < Q) sim[(size_t)(m0 + ty * 4 + i) * Q + q] = acc[i][j];
    }
}

// ---------------- K5: per-row top-8 (value desc, index asc tie-break) ------
__device__ inline bool better(double va, int ia, double vb, int ib) {
  return (va > vb) || (va == vb && ia < ib);
}

__global__ __launch_bounds__(256) void topk_kernel(const double* __restrict__ sim,
                                                   int* __restrict__ topk, int Q) {
  __shared__ double sv[256][8];
  __shared__ int    si[256][8];
  const int b = blockIdx.x, tid = threadIdx.x;
  const double* row = sim + (size_t)b * Q;
  double v[8]; int ix[8];
#pragma unroll
  for (int k = 0; k < 8; k++) { v[k] = -1e300; ix[k] = 0x7fffffff; }
  for (int q = tid; q < Q; q += 256) {
    double x = row[q];
    if (better(x, q, v[7], ix[7])) {
      v[7] = x; ix[7] = q;
#pragma unroll
      for (int k = 7; k > 0; k--) {
        if (better(v[k], ix[k], v[k - 1], ix[k - 1])) {
          double tv = v[k]; v[k] = v[k - 1]; v[k - 1] = tv;
          int    ti = ix[k]; ix[k] = ix[k - 1]; ix[k - 1] = ti;
        }
      }
    }
  }
#pragma unroll
  for (int k = 0; k < 8; k++) { sv[tid][k] = v[k]; si[tid][k] = ix[k]; }
  __syncthreads();
  for (int stride = 128; stride >= 1; stride >>= 1) {
    if (tid < stride) {
      double ov[8]; int oi[8];
      int pa = 0, pb = 0;
#pragma unroll
      for (int k = 0; k < 8; k++) {
        double va = sv[tid][pa];           int ia = si[tid][pa];
        double vb = sv[tid + stride][pb];  int ib = si[tid + stride][pb];
        if (better(va, ia, vb, ib)) { ov[k] = va; oi[k] = ia; pa++; }
        else                        { ov[k] = vb; oi[k] = ib; pb++; }
      }
#pragma unroll
      for (int k = 0; k < 8; k++) { sv[tid][k] = ov[k]; si[tid][k] = oi[k]; }
    }
    __syncthreads();
  }
  if (tid < 8) topk[b * 8 + tid] = si[0][tid];
}

// ---------------- K6: gather rows to output + positive + pos_sim -----------
__global__ __launch_bounds__(256) void gather_pos(const float* __restrict__ SUPn,
                                                  const float* __restrict__ TSn,
                                                  const int* __restrict__ topk,
                                                  float* __restrict__ out,
                                                  double* __restrict__ pos_sim, int Q) {
  __shared__ int idx[8];
  __shared__ double red[4];
  const int b = blockIdx.x, tid = threadIdx.x;
  if (tid < 8) idx[tid] = topk[b * 8 + tid];
  __syncthreads();
  float mean[3] = {0.f, 0.f, 0.f};
#pragma unroll
  for (int k = 0; k < 8; k++) {
    const float* sr = SUPn + (size_t)idx[k] * D;
    float* orow = out + ((size_t)b * 8 + k) * D;
#pragma unroll
    for (int j = 0; j < 3; j++) {
      float x = sr[tid + 256 * j];
      orow[tid + 256 * j] = x;
      mean[j] += x;
    }
  }
#pragma unroll
  for (int j = 0; j < 3; j++) mean[j] *= 0.125f;
  double ss = 0.0;
#pragma unroll
  for (int j = 0; j < 3; j++) ss += (double)mean[j] * mean[j];
  ss = blk_sum(ss, red);
  double inv = 1.0 / fmax(sqrt(ss), 1e-12);
  double dot = 0.0;
#pragma unroll
  for (int j = 0; j < 3; j++)
    dot += (double)TSn[(size_t)b * D + tid + 256 * j] * ((double)mean[j] * inv);
  dot = blk_sum(dot, red);
  if (tid == 0) pos_sim[b] = dot / (double)0.07f;
}

// ---------------- K7: per-row NNCL logsumexp --------------------------------
__global__ __launch_bounds__(256) void nncl_rows(const float* __restrict__ TSn,
                                                 const double* __restrict__ pos_sim,
                                                 double* __restrict__ row_loss) {
  __shared__ float tsb[D];
  __shared__ double red[4];
  const int b = blockIdx.x, c = threadIdx.x;
#pragma unroll
  for (int j = 0; j < 3; j++) tsb[c + 256 * j] = TSn[(size_t)b * D + c + 256 * j];
  __syncthreads();
  const float* tc = TSn + (size_t)c * D;
  double dot = 0.0;
  for (int e = 0; e < D; e += 4) {
    float4 t4 = *(const float4*)(tc + e);
    dot += (double)tsb[e] * t4.x + (double)tsb[e + 1] * t4.y +
           (double)tsb[e + 2] * t4.z + (double)tsb[e + 3] * t4.w;
  }
  const bool diag = (c == b);
  double logit = dot / (double)0.07f;
  double p = pos_sim[b];
  double m = blk_max(diag ? -1e300 : logit, red);
  m = fmax(m, p);
  double term = diag ? 0.0 : exp(logit - m);
  double ssum = blk_sum(term, red);
  ssum += exp(p - m);
  if (c == 0) row_loss[b] = (log(ssum) + m) - p;
}

// ---------------- K8: finalize scalars --------------------------------------
__global__ __launch_bounds__(256) void finalize(const float* __restrict__ maxsim,
                                                const double* __restrict__ row_loss,
                                                float* __restrict__ d_out, int out_size,
                                                int V, int B) {
  __shared__ double red[4];
  const int tid = threadIdx.x;
  double s1 = 0.0;
  for (int v = tid; v < V; v += 256) s1 += 2.0 - 2.0 * (double)maxsim[v];
  s1 = blk_sum(s1, red);
  __syncthreads();
  double s2 = 0.0;
  for (int b = tid; b < B; b += 256) s2 += row_loss[b];
  s2 = blk_sum(s2, red);
  if (tid == 0) {
    d_out[out_size - 2] = (float)(s1 / ((double)V * (double)D));
    d_out[out_size - 1] = (float)(s2 / (double)B);
  }
}

// ---------------- host launcher ---------------------------------------------
extern "C" void kernel_launch(void* const* d_in, const int* in_sizes, int n_in,
                              void* d_out, int out_size, void* d_ws, size_t ws_size,
                              hipStream_t stream) {
  const float* TS  = (const float*)d_in[0];
  const float* W   = (const float*)d_in[1];
  const float* T   = (const float*)d_in[2];
  const float* SUP = (const float*)d_in[3];
  const int B = in_sizes[0] / D;   // 256
  const int V = in_sizes[1] / D;   // 50257
  const int U = in_sizes[2] / D;   // 1000
  const int Q = in_sizes[3] / D;   // 10000
  const int VPAD = (V + 63) & ~63; // 50304
  const int NT   = (U + 15) / 16;  // 63
  const int UPAD = NT * 16;        // 1008

  char* ws = (char*)d_ws;
  size_t off = 0;
  auto alloc = [&](size_t bytes) -> char* {
    char* p = ws + off;
    off = (off + bytes + 255) & ~(size_t)255;
    return p;
  };
  bf16_t* w_bf   = (bf16_t*)alloc((size_t)VPAD * D * 2);
  bf16_t* t_bf   = (bf16_t*)alloc((size_t)UPAD * D * 2);
  float*  maxsim = (float*) alloc((size_t)VPAD * 4);
  float*  ts_n   = (float*) alloc((size_t)B * D * 4);
  float*  sup_n  = (float*) alloc((size_t)Q * D * 4);
  double* simd   = (double*)alloc((size_t)B * Q * 8);
  int*    tki    = (int*)   alloc((size_t)B * 8 * 4);
  double* psim   = (double*)alloc((size_t)B * 8);
  double* rloss  = (double*)alloc((size_t)B * 8);
  (void)ws_size; (void)n_in;

  norm_rows<true ><<<VPAD / 4, 256, 0, stream>>>(W,   w_bf,  V, VPAD);
  norm_rows<true ><<<UPAD / 4, 256, 0, stream>>>(T,   t_bf,  U, UPAD);
  norm_rows<false><<<B    / 4, 256, 0, stream>>>(TS,  ts_n,  B, B);
  norm_rows<false><<<Q    / 4, 256, 0, stream>>>(SUP, sup_n, Q, Q);

  maxsim_gemm<<<VPAD / 64, 256, 0, stream>>>(w_bf, t_bf, maxsim, V, U, NT);

  dim3 g4((Q + 63) / 64, B / 64);
  sim_bq_gemm<<<g4, 256, 0, stream>>>(ts_n, sup_n, simd, Q);

  topk_kernel<<<B, 256, 0, stream>>>(simd, tki, Q);
  gather_pos<<<B, 256, 0, stream>>>(sup_n, ts_n, tki, (float*)d_out, psim, Q);
  nncl_rows<<<B, 256, 0, stream>>>(ts_n, psim, rloss);
  finalize<<<1, 256, 0, stream>>>(maxsim, rloss, (float*)d_out, out_size, V, B);
}

// Round 2
// 357.711 us; speedup vs baseline: 1.5667x; 1.5667x over previous
//
#include <hip/hip_runtime.h>
#include <hip/hip_bf16.h>
#include <math.h>

typedef __bf16 bf16_t;
typedef __bf16 bf16x8 __attribute__((ext_vector_type(8)));
typedef __bf16 bf16x4 __attribute__((ext_vector_type(4)));
typedef float  f32x4  __attribute__((ext_vector_type(4)));

#define D 768

// ---------------- block reduction helpers (blockDim == 256) ----------------
__device__ inline double blk_sum(double x, double* s) {
#pragma unroll
  for (int m = 32; m; m >>= 1) x += __shfl_xor(x, m);
  __syncthreads();
  if ((threadIdx.x & 63) == 0) s[threadIdx.x >> 6] = x;
  __syncthreads();
  return s[0] + s[1] + s[2] + s[3];
}

__device__ inline double blk_max(double x, double* s) {
#pragma unroll
  for (int m = 32; m; m >>= 1) x = fmax(x, __shfl_xor(x, m));
  __syncthreads();
  if ((threadIdx.x & 63) == 0) s[threadIdx.x >> 6] = x;
  __syncthreads();
  return fmax(fmax(s[0], s[1]), fmax(s[2], s[3]));
}

// ---------------- K1: L2-normalize rows (f64-accumulated norm) -------------
// One wave per row (4 rows / 256-thread block). Pad rows -> zeros (bf16 out).
// Either dst may be null.
__global__ __launch_bounds__(256) void norm_rows(const float* __restrict__ src,
                                                 float* __restrict__ dst_f32,
                                                 bf16_t* __restrict__ dst_bf,
                                                 int n_valid, int n_total) {
  int row  = blockIdx.x * 4 + (threadIdx.x >> 6);
  int lane = threadIdx.x & 63;
  if (row >= n_total) return;
  if (row >= n_valid) {
    if (dst_bf) {
      bf16_t* drow = dst_bf + (size_t)row * D;
      bf16x4 z = {(bf16_t)0.f, (bf16_t)0.f, (bf16_t)0.f, (bf16_t)0.f};
#pragma unroll
      for (int j = 0; j < 3; j++) *(bf16x4*)(drow + 4 * (lane + 64 * j)) = z;
    }
    return;
  }
  const float4* s = (const float4*)(src + (size_t)row * D);
  float4 v[3];
  double ss = 0.0;
#pragma unroll
  for (int j = 0; j < 3; j++) {
    v[j] = s[lane + 64 * j];
    ss += (double)v[j].x * v[j].x + (double)v[j].y * v[j].y +
          (double)v[j].z * v[j].z + (double)v[j].w * v[j].w;
  }
#pragma unroll
  for (int m = 32; m; m >>= 1) ss += __shfl_xor(ss, m);
  double inv = 1.0 / fmax(sqrt(ss), 1e-12);
  float4 o[3];
#pragma unroll
  for (int j = 0; j < 3; j++) {
    o[j].x = (float)((double)v[j].x * inv);
    o[j].y = (float)((double)v[j].y * inv);
    o[j].z = (float)((double)v[j].z * inv);
    o[j].w = (float)((double)v[j].w * inv);
  }
  if (dst_f32) {
    float* drow = dst_f32 + (size_t)row * D;
#pragma unroll
    for (int j = 0; j < 3; j++) ((float4*)drow)[lane + 64 * j] = o[j];
  }
  if (dst_bf) {
    bf16_t* drow = dst_bf + (size_t)row * D;
#pragma unroll
    for (int j = 0; j < 3; j++) {
      bf16x4 ob;
      ob[0] = (bf16_t)o[j].x; ob[1] = (bf16_t)o[j].y;
      ob[2] = (bf16_t)o[j].z; ob[3] = (bf16_t)o[j].w;
      *(bf16x4*)(drow + 4 * (lane + 64 * j)) = ob;
    }
  }
}

// ---------------- K2: max-sim GEMM (bf16 MFMA, fused row-max) ---------------
#define LDSROW 776  // 768 + 8 pad (bf16 units)

__global__ __launch_bounds__(256) void maxsim_gemm(const bf16_t* __restrict__ Wb,
                                                   const bf16_t* __restrict__ Tb,
                                                   float* __restrict__ maxsim,
                                                   int V, int U, int NT) {
  __shared__ __align__(16) bf16_t lds[2][16 * LDSROW];
  const int tid  = threadIdx.x;
  const int lane = tid & 63;
  const int rowbase = blockIdx.x * 64 + (tid >> 6) * 16;

  bf16x8 a[24];
  const bf16_t* arow = Wb + (size_t)(rowbase + (lane & 15)) * D + ((lane >> 4) * 8);
#pragma unroll
  for (int kk = 0; kk < 24; kk++) a[kk] = *(const bf16x8*)(arow + kk * 32);

  auto stage = [&](int buf, int nt) {
    const ulonglong2* src = (const ulonglong2*)(Tb + (size_t)nt * 16 * D);
#pragma unroll
    for (int j = 0; j < 6; j++) {
      int c = tid + j * 256;        // 1536 x 16B chunks
      int r = c / 96, w = c % 96;   // 96 chunks per row
      *(ulonglong2*)&lds[buf][r * LDSROW + w * 8] = src[c];
    }
  };

  f32x4 mx = {-1e30f, -1e30f, -1e30f, -1e30f};
  stage(0, 0);
  for (int nt = 0; nt < NT; nt++) {
    __syncthreads();
    if (nt + 1 < NT) stage((nt + 1) & 1, nt + 1);
    f32x4 acc = {0.f, 0.f, 0.f, 0.f};
    const bf16_t* brow = &lds[nt & 1][(lane & 15) * LDSROW + ((lane >> 4) * 8)];
#pragma unroll
    for (int kk = 0; kk < 24; kk++) {
      bf16x8 b = *(const bf16x8*)(brow + kk * 32);
      acc = __builtin_amdgcn_mfma_f32_16x16x32_bf16(a[kk], b, acc, 0, 0, 0);
    }
    if (nt * 16 + (lane & 15) < U) {
#pragma unroll
      for (int j = 0; j < 4; j++) mx[j] = fmaxf(mx[j], acc[j]);
    }
  }
#pragma unroll
  for (int m = 1; m < 16; m <<= 1) {
#pragma unroll
    for (int j = 0; j < 4; j++) mx[j] = fmaxf(mx[j], __shfl_xor(mx[j], m));
  }
  if ((lane & 15) == 0) {
    int r0 = rowbase + (lane >> 4) * 4;
#pragma unroll
    for (int j = 0; j < 4; j++)
      if (r0 + j < V) maxsim[r0 + j] = mx[j];
  }
}

// ---------------- K3: approx sim GEMM (bf16 MFMA) ---------------------------
// A = sup rows (reg-resident, converted f32->bf16 at load), B = ts tiles.
// Writes f32 sims sim[b][q], ld = QPAD.
__global__ __launch_bounds__(256) void simf_gemm(const float* __restrict__ SUPn,
                                                 const bf16_t* __restrict__ TSb,
                                                 float* __restrict__ sim,
                                                 int Q, int ld, int NTB) {
  __shared__ __align__(16) bf16_t lds[2][16 * LDSROW];
  const int tid  = threadIdx.x;
  const int lane = tid & 63;
  const int rowbase = blockIdx.x * 64 + (tid >> 6) * 16;
  const int arow_i  = rowbase + (lane & 15);

  bf16x8 a[24];
  if (arow_i < Q) {
    const float* ar = SUPn + (size_t)arow_i * D + ((lane >> 4) * 8);
#pragma unroll
    for (int kk = 0; kk < 24; kk++) {
      float4 x = *(const float4*)(ar + kk * 32);
      float4 y = *(const float4*)(ar + kk * 32 + 4);
      bf16x8 f;
      f[0] = (bf16_t)x.x; f[1] = (bf16_t)x.y; f[2] = (bf16_t)x.z; f[3] = (bf16_t)x.w;
      f[4] = (bf16_t)y.x; f[5] = (bf16_t)y.y; f[6] = (bf16_t)y.z; f[7] = (bf16_t)y.w;
      a[kk] = f;
    }
  } else {
#pragma unroll
    for (int kk = 0; kk < 24; kk++) {
      bf16x8 f;
#pragma unroll
      for (int e = 0; e < 8; e++) f[e] = (bf16_t)0.f;
      a[kk] = f;
    }
  }

  auto stage = [&](int buf, int nt) {
    const ulonglong2* src = (const ulonglong2*)(TSb + (size_t)nt * 16 * D);
#pragma unroll
    for (int j = 0; j < 6; j++) {
      int c = tid + j * 256;
      int r = c / 96, w = c % 96;
      *(ulonglong2*)&lds[buf][r * LDSROW + w * 8] = src[c];
    }
  };

  stage(0, 0);
  for (int nt = 0; nt < NTB; nt++) {
    __syncthreads();
    if (nt + 1 < NTB) stage((nt + 1) & 1, nt + 1);
    f32x4 acc = {0.f, 0.f, 0.f, 0.f};
    const bf16_t* brow = &lds[nt & 1][(lane & 15) * LDSROW + ((lane >> 4) * 8)];
#pragma unroll
    for (int kk = 0; kk < 24; kk++) {
      bf16x8 b = *(const bf16x8*)(brow + kk * 32);
      acc = __builtin_amdgcn_mfma_f32_16x16x32_bf16(a[kk], b, acc, 0, 0, 0);
    }
    // C layout: col (ts index b) = lane&15, row (sup index q) = (lane>>4)*4+j
    const int bcol = nt * 16 + (lane & 15);
    const int q0   = rowbase + ((lane >> 4) << 2);
    float* dst = sim + (size_t)bcol * ld + q0;
    if (q0 + 3 < Q) {
      *(f32x4*)dst = acc;
    } else {
#pragma unroll
      for (int j = 0; j < 4; j++)
        if (q0 + j < Q) dst[j] = acc[j];
    }
  }
}

// ---------------- K4: per-row top-16 on f32 sims (packed u64 keys) ----------
__device__ inline unsigned long long pack_key(float v, int q) {
  unsigned u = __float_as_uint(v);
  u = (u & 0x80000000u) ? ~u : (u | 0x80000000u);  // order-preserving map
  return ((unsigned long long)u << 32) | (unsigned)(0xFFFFFFFFu - (unsigned)q);
}

__global__ __launch_bounds__(256) void topk16_f32(const float* __restrict__ sim,
                                                  int* __restrict__ cand,
                                                  int Q, int ld) {
  __shared__ unsigned long long sk[256][16];
  const int b = blockIdx.x, tid = threadIdx.x;
  const float* row = sim + (size_t)b * ld;
  unsigned long long best[16];
#pragma unroll
  for (int k = 0; k < 16; k++) best[k] = 0ull;
  for (int q = tid; q < Q; q += 256) {
    unsigned long long key = pack_key(row[q], q);
    if (key > best[15]) {
      best[15] = key;
      for (int k = 15; k > 0; k--) {
        if (best[k] > best[k - 1]) {
          unsigned long long t = best[k]; best[k] = best[k - 1]; best[k - 1] = t;
        } else break;
      }
    }
  }
#pragma unroll
  for (int k = 0; k < 16; k++) sk[tid][k] = best[k];
  for (int stride = 128; stride >= 1; stride >>= 1) {
    __syncthreads();
    if (tid < stride) {
      unsigned long long out[16];
      int pa = 0, pb = 0;
#pragma unroll
      for (int k = 0; k < 16; k++) {
        unsigned long long va = sk[tid][pa], vb = sk[tid + stride][pb];
        if (va >= vb) { out[k] = va; pa++; }
        else          { out[k] = vb; pb++; }
      }
#pragma unroll
      for (int k = 0; k < 16; k++) sk[tid][k] = out[k];
    }
  }
  __syncthreads();
  if (tid < 16)
    cand[b * 16 + tid] = (int)(0xFFFFFFFFu - (unsigned)(sk[0][tid] & 0xFFFFFFFFull));
}

// ---------------- K5: exact f64 rescore of 16 candidates -> top-8 ----------
__global__ __launch_bounds__(256) void rescore(const float* __restrict__ SUPn,
                                               const float* __restrict__ TSn,
                                               const int* __restrict__ cand,
                                               int* __restrict__ topk) {
  __shared__ float tsrow[D];
  __shared__ double sval[16];
  __shared__ int    sidx[16];
  const int b = blockIdx.x, tid = threadIdx.x;
  const int lane = tid & 63, w = tid >> 6;
#pragma unroll
  for (int j = 0; j < 3; j++) tsrow[tid + 256 * j] = TSn[(size_t)b * D + tid + 256 * j];
  __syncthreads();
  for (int c = w; c < 16; c += 4) {
    int q = cand[b * 16 + c];
    const float* sr = SUPn + (size_t)q * D;
    double dot = 0.0;
#pragma unroll
    for (int i = 0; i < 12; i++)
      dot += (double)sr[lane + 64 * i] * (double)tsrow[lane + 64 * i];
#pragma unroll
    for (int m = 32; m; m >>= 1) dot += __shfl_xor(dot, m);
    if (lane == 0) { sval[c] = dot; sidx[c] = q; }
  }
  __syncthreads();
  if (tid == 0) {
    // insertion sort: value desc, index asc
    for (int i = 1; i < 16; i++) {
      double v = sval[i]; int ix = sidx[i];
      int j = i - 1;
      while (j >= 0 && (sval[j] < v || (sval[j] == v && sidx[j] > ix))) {
        sval[j + 1] = sval[j]; sidx[j + 1] = sidx[j]; j--;
      }
      sval[j + 1] = v; sidx[j + 1] = ix;
    }
#pragma unroll
    for (int k = 0; k < 8; k++) topk[b * 8 + k] = sidx[k];
  }
}

// ---------------- K6: gather rows to output + positive + pos_sim -----------
__global__ __launch_bounds__(256) void gather_pos(const float* __restrict__ SUPn,
                                                  const float* __restrict__ TSn,
                                                  const int* __restrict__ topk,
                                                  float* __restrict__ out,
                                                  double* __restrict__ pos_sim, int Q) {
  __shared__ int idx[8];
  __shared__ double red[4];
  const int b = blockIdx.x, tid = threadIdx.x;
  if (tid < 8) idx[tid] = topk[b * 8 + tid];
  __syncthreads();
  float mean[3] = {0.f, 0.f, 0.f};
#pragma unroll
  for (int k = 0; k < 8; k++) {
    const float* sr = SUPn + (size_t)idx[k] * D;
    float* orow = out + ((size_t)b * 8 + k) * D;
#pragma unroll
    for (int j = 0; j < 3; j++) {
      float x = sr[tid + 256 * j];
      orow[tid + 256 * j] = x;
      mean[j] += x;
    }
  }
#pragma unroll
  for (int j = 0; j < 3; j++) mean[j] *= 0.125f;
  double ss = 0.0;
#pragma unroll
  for (int j = 0; j < 3; j++) ss += (double)mean[j] * mean[j];
  ss = blk_sum(ss, red);
  double inv = 1.0 / fmax(sqrt(ss), 1e-12);
  double dot = 0.0;
#pragma unroll
  for (int j = 0; j < 3; j++)
    dot += (double)TSn[(size_t)b * D + tid + 256 * j] * ((double)mean[j] * inv);
  dot = blk_sum(dot, red);
  if (tid == 0) pos_sim[b] = dot / (double)0.07f;
}

// ---------------- K7: per-row NNCL logsumexp --------------------------------
__global__ __launch_bounds__(256) void nncl_rows(const float* __restrict__ TSn,
                                                 const double* __restrict__ pos_sim,
                                                 double* __restrict__ row_loss) {
  __shared__ float tsb[D];
  __shared__ double red[4];
  const int b = blockIdx.x, c = threadIdx.x;
#pragma unroll
  for (int j = 0; j < 3; j++) tsb[c + 256 * j] = TSn[(size_t)b * D + c + 256 * j];
  __syncthreads();
  const float* tc = TSn + (size_t)c * D;
  double dot = 0.0;
  for (int e = 0; e < D; e += 4) {
    float4 t4 = *(const float4*)(tc + e);
    dot += (double)tsb[e] * t4.x + (double)tsb[e + 1] * t4.y +
           (double)tsb[e + 2] * t4.z + (double)tsb[e + 3] * t4.w;
  }
  const bool diag = (c == b);
  double logit = dot / (double)0.07f;
  double p = pos_sim[b];
  double m = blk_max(diag ? -1e300 : logit, red);
  m = fmax(m, p);
  double term = diag ? 0.0 : exp(logit - m);
  double ssum = blk_sum(term, red);
  ssum += exp(p - m);
  if (c == 0) row_loss[b] = (log(ssum) + m) - p;
}

// ---------------- K8: finalize scalars --------------------------------------
__global__ __launch_bounds__(256) void finalize(const float* __restrict__ maxsim,
                                                const double* __restrict__ row_loss,
                                                float* __restrict__ d_out, int out_size,
                                                int V, int B) {
  __shared__ double red[4];
  const int tid = threadIdx.x;
  double s1 = 0.0;
  for (int v = tid; v < V; v += 256) s1 += 2.0 - 2.0 * (double)maxsim[v];
  s1 = blk_sum(s1, red);
  __syncthreads();
  double s2 = 0.0;
  for (int b = tid; b < B; b += 256) s2 += row_loss[b];
  s2 = blk_sum(s2, red);
  if (tid == 0) {
    d_out[out_size - 2] = (float)(s1 / ((double)V * (double)D));
    d_out[out_size - 1] = (float)(s2 / (double)B);
  }
}

// ---------------- host launcher ---------------------------------------------
extern "C" void kernel_launch(void* const* d_in, const int* in_sizes, int n_in,
                              void* d_out, int out_size, void* d_ws, size_t ws_size,
                              hipStream_t stream) {
  const float* TS  = (const float*)d_in[0];
  const float* W   = (const float*)d_in[1];
  const float* T   = (const float*)d_in[2];
  const float* SUP = (const float*)d_in[3];
  const int B = in_sizes[0] / D;   // 256
  const int V = in_sizes[1] / D;   // 50257
  const int U = in_sizes[2] / D;   // 1000
  const int Q = in_sizes[3] / D;   // 10000
  const int VPAD = (V + 63) & ~63; // 50304
  const int NT   = (U + 15) / 16;  // 63
  const int UPAD = NT * 16;        // 1008
  const int QPAD = (Q + 63) & ~63; // 10048
  const int NTB  = B / 16;         // 16

  char* ws = (char*)d_ws;
  size_t off = 0;
  auto alloc = [&](size_t bytes) -> char* {
    char* p = ws + off;
    off = (off + bytes + 255) & ~(size_t)255;
    return p;
  };
  bf16_t* w_bf   = (bf16_t*)alloc((size_t)VPAD * D * 2);
  bf16_t* t_bf   = (bf16_t*)alloc((size_t)UPAD * D * 2);
  float*  maxsim = (float*) alloc((size_t)VPAD * 4);
  float*  ts_n   = (float*) alloc((size_t)B * D * 4);
  bf16_t* ts_bf  = (bf16_t*)alloc((size_t)B * D * 2);
  float*  sup_n  = (float*) alloc((size_t)Q * D * 4);
  float*  simf   = (float*) alloc((size_t)B * QPAD * 4);
  int*    cand   = (int*)   alloc((size_t)B * 16 * 4);
  int*    tki    = (int*)   alloc((size_t)B * 8 * 4);
  double* psim   = (double*)alloc((size_t)B * 8);
  double* rloss  = (double*)alloc((size_t)B * 8);
  (void)ws_size; (void)n_in;

  norm_rows<<<VPAD / 4, 256, 0, stream>>>(W,   nullptr, w_bf,  V, VPAD);
  norm_rows<<<UPAD / 4, 256, 0, stream>>>(T,   nullptr, t_bf,  U, UPAD);
  norm_rows<<<B    / 4, 256, 0, stream>>>(TS,  ts_n,  ts_bf,   B, B);
  norm_rows<<<(Q + 3) / 4, 256, 0, stream>>>(SUP, sup_n, nullptr, Q, Q);

  maxsim_gemm<<<VPAD / 64, 256, 0, stream>>>(w_bf, t_bf, maxsim, V, U, NT);

  simf_gemm<<<QPAD / 64, 256, 0, stream>>>(sup_n, ts_bf, simf, Q, QPAD, NTB);
  topk16_f32<<<B, 256, 0, stream>>>(simf, cand, Q, QPAD);
  rescore<<<B, 256, 0, stream>>>(sup_n, ts_n, cand, tki);

  gather_pos<<<B, 256, 0, stream>>>(sup_n, ts_n, tki, (float*)d_out, psim, Q);
  nncl_rows<<<B, 256, 0, stream>>>(ts_n, psim, rloss);
  finalize<<<1, 256, 0, stream>>>(maxsim, rloss, (float*)d_out, out_size, V, B);
}

// Round 3
// 353.081 us; speedup vs baseline: 1.5873x; 1.0131x over previous
//
#include <hip/hip_runtime.h>
#include <hip/hip_bf16.h>
#include <math.h>

typedef __bf16 bf16_t;
typedef __bf16 bf16x8 __attribute__((ext_vector_type(8)));
typedef __bf16 bf16x4 __attribute__((ext_vector_type(4)));
typedef float  f32x4  __attribute__((ext_vector_type(4)));

#define D 768

// ---------------- block reduction helpers (blockDim == 256) ----------------
__device__ inline double blk_sum(double x, double* s) {
#pragma unroll
  for (int m = 32; m; m >>= 1) x += __shfl_xor(x, m);
  __syncthreads();
  if ((threadIdx.x & 63) == 0) s[threadIdx.x >> 6] = x;
  __syncthreads();
  return s[0] + s[1] + s[2] + s[3];
}

__device__ inline double blk_max(double x, double* s) {
#pragma unroll
  for (int m = 32; m; m >>= 1) x = fmax(x, __shfl_xor(x, m));
  __syncthreads();
  if ((threadIdx.x & 63) == 0) s[threadIdx.x >> 6] = x;
  __syncthreads();
  return fmax(fmax(s[0], s[1]), fmax(s[2], s[3]));
}

// ---------------- K1: L2-normalize rows (f64-accumulated norm) -------------
__global__ __launch_bounds__(256) void norm_rows(const float* __restrict__ src,
                                                 float* __restrict__ dst_f32,
                                                 bf16_t* __restrict__ dst_bf,
                                                 int n_valid, int n_total) {
  int row  = blockIdx.x * 4 + (threadIdx.x >> 6);
  int lane = threadIdx.x & 63;
  if (row >= n_total) return;
  if (row >= n_valid) {
    if (dst_bf) {
      bf16_t* drow = dst_bf + (size_t)row * D;
      bf16x4 z = {(bf16_t)0.f, (bf16_t)0.f, (bf16_t)0.f, (bf16_t)0.f};
#pragma unroll
      for (int j = 0; j < 3; j++) *(bf16x4*)(drow + 4 * (lane + 64 * j)) = z;
    }
    return;
  }
  const float4* s = (const float4*)(src + (size_t)row * D);
  float4 v[3];
  double ss = 0.0;
#pragma unroll
  for (int j = 0; j < 3; j++) {
    v[j] = s[lane + 64 * j];
    ss += (double)v[j].x * v[j].x + (double)v[j].y * v[j].y +
          (double)v[j].z * v[j].z + (double)v[j].w * v[j].w;
  }
#pragma unroll
  for (int m = 32; m; m >>= 1) ss += __shfl_xor(ss, m);
  double inv = 1.0 / fmax(sqrt(ss), 1e-12);
  float4 o[3];
#pragma unroll
  for (int j = 0; j < 3; j++) {
    o[j].x = (float)((double)v[j].x * inv);
    o[j].y = (float)((double)v[j].y * inv);
    o[j].z = (float)((double)v[j].z * inv);
    o[j].w = (float)((double)v[j].w * inv);
  }
  if (dst_f32) {
    float* drow = dst_f32 + (size_t)row * D;
#pragma unroll
    for (int j = 0; j < 3; j++) ((float4*)drow)[lane + 64 * j] = o[j];
  }
  if (dst_bf) {
    bf16_t* drow = dst_bf + (size_t)row * D;
#pragma unroll
    for (int j = 0; j < 3; j++) {
      bf16x4 ob;
      ob[0] = (bf16_t)o[j].x; ob[1] = (bf16_t)o[j].y;
      ob[2] = (bf16_t)o[j].z; ob[3] = (bf16_t)o[j].w;
      *(bf16x4*)(drow + 4 * (lane + 64 * j)) = ob;
    }
  }
}

// ---------------- K2: max-sim GEMM v2 ---------------------------------------
// 128 rows/block = 4 waves x 32 rows (2 row-tiles of 16, A in 192 VGPRs).
// W read raw f32 (norm fused: f64 row-norm accumulated during A-load; final
// row max divided by the norm). B = 16-proto bf16 tiles double-buffered in
// LDS. Each B-fragment read feeds 2 MFMAs (one per row-tile); accumulators
// split even/odd-k for 4 independent MFMA chains per wave.
#define LDSROW 776  // 768 + 8 pad (bf16 units)

__global__ __launch_bounds__(256, 2) void maxsim_gemm(
    const float* __restrict__ W, const bf16_t* __restrict__ Tb,
    float* __restrict__ maxsim, int V, int U, int NT) {
  __shared__ __align__(16) bf16_t lds[2][16 * LDSROW];
  const int tid  = threadIdx.x;
  const int lane = tid & 63;
  const int r    = lane & 15;   // row-within-tile on A side, col on C side
  const int ks   = lane >> 4;   // k-slice 0..3
  const int rowbase = blockIdx.x * 128 + (tid >> 6) * 32;
  const int row0 = rowbase + r;
  const int row1 = rowbase + 16 + r;

  // ---- A load + fused norm ----
  bf16x8 a0[24], a1[24];
  double ss0 = 0.0, ss1 = 0.0;
  {
    const float* p0 = W + (size_t)row0 * D + ks * 8;
    const float* p1 = W + (size_t)row1 * D + ks * 8;
    const bool v0 = row0 < V, v1 = row1 < V;
#pragma unroll
    for (int kk = 0; kk < 24; kk++) {
      bf16x8 f;
      if (v0) {
        float4 x = *(const float4*)(p0 + kk * 32);
        float4 y = *(const float4*)(p0 + kk * 32 + 4);
        ss0 += (double)x.x * x.x + (double)x.y * x.y + (double)x.z * x.z +
               (double)x.w * x.w + (double)y.x * y.x + (double)y.y * y.y +
               (double)y.z * y.z + (double)y.w * y.w;
        f[0] = (bf16_t)x.x; f[1] = (bf16_t)x.y; f[2] = (bf16_t)x.z; f[3] = (bf16_t)x.w;
        f[4] = (bf16_t)y.x; f[5] = (bf16_t)y.y; f[6] = (bf16_t)y.z; f[7] = (bf16_t)y.w;
      } else {
#pragma unroll
        for (int e = 0; e < 8; e++) f[e] = (bf16_t)0.f;
      }
      a0[kk] = f;
      if (v1) {
        float4 x = *(const float4*)(p1 + kk * 32);
        float4 y = *(const float4*)(p1 + kk * 32 + 4);
        ss1 += (double)x.x * x.x + (double)x.y * x.y + (double)x.z * x.z +
               (double)x.w * x.w + (double)y.x * y.x + (double)y.y * y.y +
               (double)y.z * y.z + (double)y.w * y.w;
        f[0] = (bf16_t)x.x; f[1] = (bf16_t)x.y; f[2] = (bf16_t)x.z; f[3] = (bf16_t)x.w;
        f[4] = (bf16_t)y.x; f[5] = (bf16_t)y.y; f[6] = (bf16_t)y.z; f[7] = (bf16_t)y.w;
      } else {
#pragma unroll
        for (int e = 0; e < 8; e++) f[e] = (bf16_t)0.f;
      }
      a1[kk] = f;
    }
  }
  ss0 += __shfl_xor(ss0, 16); ss0 += __shfl_xor(ss0, 32);
  ss1 += __shfl_xor(ss1, 16); ss1 += __shfl_xor(ss1, 32);
  const double inv0 = 1.0 / fmax(sqrt(ss0), 1e-12);
  const double inv1 = 1.0 / fmax(sqrt(ss1), 1e-12);

  auto stage = [&](int buf, int nt) {
    const ulonglong2* src = (const ulonglong2*)(Tb + (size_t)nt * 16 * D);
#pragma unroll
    for (int j = 0; j < 6; j++) {
      int c = tid + j * 256;        // 1536 x 16B chunks
      int rr = c / 96, w = c % 96;  // 96 chunks per row
      *(ulonglong2*)&lds[buf][rr * LDSROW + w * 8] = src[c];
    }
  };

  f32x4 mx0 = {-1e30f, -1e30f, -1e30f, -1e30f};
  f32x4 mx1 = {-1e30f, -1e30f, -1e30f, -1e30f};
  stage(0, 0);
  for (int nt = 0; nt < NT; nt++) {
    __syncthreads();
    if (nt + 1 < NT) stage((nt + 1) & 1, nt + 1);
    f32x4 acc0e = {0.f,0.f,0.f,0.f}, acc0o = {0.f,0.f,0.f,0.f};
    f32x4 acc1e = {0.f,0.f,0.f,0.f}, acc1o = {0.f,0.f,0.f,0.f};
    const bf16_t* brow = &lds[nt & 1][r * LDSROW + ks * 8];
#pragma unroll
    for (int kk = 0; kk < 24; kk += 2) {
      bf16x8 be = *(const bf16x8*)(brow + kk * 32);
      bf16x8 bo = *(const bf16x8*)(brow + kk * 32 + 32);
      acc0e = __builtin_amdgcn_mfma_f32_16x16x32_bf16(a0[kk],     be, acc0e, 0, 0, 0);
      acc1e = __builtin_amdgcn_mfma_f32_16x16x32_bf16(a1[kk],     be, acc1e, 0, 0, 0);
      acc0o = __builtin_amdgcn_mfma_f32_16x16x32_bf16(a0[kk + 1], bo, acc0o, 0, 0, 0);
      acc1o = __builtin_amdgcn_mfma_f32_16x16x32_bf16(a1[kk + 1], bo, acc1o, 0, 0, 0);
    }
    if (nt * 16 + r < U) {
#pragma unroll
      for (int j = 0; j < 4; j++) {
        mx0[j] = fmaxf(mx0[j], acc0e[j] + acc0o[j]);
        mx1[j] = fmaxf(mx1[j], acc1e[j] + acc1o[j]);
      }
    }
  }
  // reduce across the 16 col-lanes (C layout: col=lane&15, row=ks*4+j)
#pragma unroll
  for (int m = 1; m < 16; m <<= 1) {
#pragma unroll
    for (int j = 0; j < 4; j++) {
      mx0[j] = fmaxf(mx0[j], __shfl_xor(mx0[j], m));
      mx1[j] = fmaxf(mx1[j], __shfl_xor(mx1[j], m));
    }
  }
#pragma unroll
  for (int j = 0; j < 4; j++) {
    int rr = ks * 4 + j;
    double i0 = __shfl(inv0, rr);  // norm of row rowbase+rr lives in lane rr
    double i1 = __shfl(inv1, rr);
    if (r == 0) {
      if (rowbase + rr < V)      maxsim[rowbase + rr]      = (float)((double)mx0[j] * i0);
      if (rowbase + 16 + rr < V) maxsim[rowbase + 16 + rr] = (float)((double)mx1[j] * i1);
    }
  }
}

// ---------------- K3: approx sim GEMM (bf16 MFMA) ---------------------------
__global__ __launch_bounds__(256) void simf_gemm(const float* __restrict__ SUPn,
                                                 const bf16_t* __restrict__ TSb,
                                                 float* __restrict__ sim,
                                                 int Q, int ld, int NTB) {
  __shared__ __align__(16) bf16_t lds[2][16 * LDSROW];
  const int tid  = threadIdx.x;
  const int lane = tid & 63;
  const int rowbase = blockIdx.x * 64 + (tid >> 6) * 16;
  const int arow_i  = rowbase + (lane & 15);

  bf16x8 a[24];
  if (arow_i < Q) {
    const float* ar = SUPn + (size_t)arow_i * D + ((lane >> 4) * 8);
#pragma unroll
    for (int kk = 0; kk < 24; kk++) {
      float4 x = *(const float4*)(ar + kk * 32);
      float4 y = *(const float4*)(ar + kk * 32 + 4);
      bf16x8 f;
      f[0] = (bf16_t)x.x; f[1] = (bf16_t)x.y; f[2] = (bf16_t)x.z; f[3] = (bf16_t)x.w;
      f[4] = (bf16_t)y.x; f[5] = (bf16_t)y.y; f[6] = (bf16_t)y.z; f[7] = (bf16_t)y.w;
      a[kk] = f;
    }
  } else {
#pragma unroll
    for (int kk = 0; kk < 24; kk++) {
      bf16x8 f;
#pragma unroll
      for (int e = 0; e < 8; e++) f[e] = (bf16_t)0.f;
      a[kk] = f;
    }
  }

  auto stage = [&](int buf, int nt) {
    const ulonglong2* src = (const ulonglong2*)(TSb + (size_t)nt * 16 * D);
#pragma unroll
    for (int j = 0; j < 6; j++) {
      int c = tid + j * 256;
      int rr = c / 96, w = c % 96;
      *(ulonglong2*)&lds[buf][rr * LDSROW + w * 8] = src[c];
    }
  };

  stage(0, 0);
  for (int nt = 0; nt < NTB; nt++) {
    __syncthreads();
    if (nt + 1 < NTB) stage((nt + 1) & 1, nt + 1);
    f32x4 acc = {0.f, 0.f, 0.f, 0.f};
    const bf16_t* brow = &lds[nt & 1][(lane & 15) * LDSROW + ((lane >> 4) * 8)];
#pragma unroll
    for (int kk = 0; kk < 24; kk++) {
      bf16x8 b = *(const bf16x8*)(brow + kk * 32);
      acc = __builtin_amdgcn_mfma_f32_16x16x32_bf16(a[kk], b, acc, 0, 0, 0);
    }
    const int bcol = nt * 16 + (lane & 15);
    const int q0   = rowbase + ((lane >> 4) << 2);
    float* dst = sim + (size_t)bcol * ld + q0;
    if (q0 + 3 < Q) {
      *(f32x4*)dst = acc;
    } else {
#pragma unroll
      for (int j = 0; j < 4; j++)
        if (q0 + j < Q) dst[j] = acc[j];
    }
  }
}

// ---------------- K4: per-row top-16 on f32 sims (packed u64 keys) ----------
__device__ inline unsigned long long pack_key(float v, int q) {
  unsigned u = __float_as_uint(v);
  u = (u & 0x80000000u) ? ~u : (u | 0x80000000u);  // order-preserving map
  return ((unsigned long long)u << 32) | (unsigned)(0xFFFFFFFFu - (unsigned)q);
}

__global__ __launch_bounds__(256) void topk16_f32(const float* __restrict__ sim,
                                                  int* __restrict__ cand,
                                                  int Q, int ld) {
  __shared__ unsigned long long sk[256][16];
  const int b = blockIdx.x, tid = threadIdx.x;
  const float* row = sim + (size_t)b * ld;
  unsigned long long best[16];
#pragma unroll
  for (int k = 0; k < 16; k++) best[k] = 0ull;
  for (int q = tid; q < Q; q += 256) {
    unsigned long long key = pack_key(row[q], q);
    if (key > best[15]) {
      best[15] = key;
      for (int k = 15; k > 0; k--) {
        if (best[k] > best[k - 1]) {
          unsigned long long t = best[k]; best[k] = best[k - 1]; best[k - 1] = t;
        } else break;
      }
    }
  }
#pragma unroll
  for (int k = 0; k < 16; k++) sk[tid][k] = best[k];
  for (int stride = 128; stride >= 1; stride >>= 1) {
    __syncthreads();
    if (tid < stride) {
      unsigned long long out[16];
      int pa = 0, pb = 0;
#pragma unroll
      for (int k = 0; k < 16; k++) {
        unsigned long long va = sk[tid][pa], vb = sk[tid + stride][pb];
        if (va >= vb) { out[k] = va; pa++; }
        else          { out[k] = vb; pb++; }
      }
#pragma unroll
      for (int k = 0; k < 16; k++) sk[tid][k] = out[k];
    }
  }
  __syncthreads();
  if (tid < 16)
    cand[b * 16 + tid] = (int)(0xFFFFFFFFu - (unsigned)(sk[0][tid] & 0xFFFFFFFFull));
}

// ---------------- K5: exact f64 rescore of 16 candidates -> top-8 ----------
__global__ __launch_bounds__(256) void rescore(const float* __restrict__ SUPn,
                                               const float* __restrict__ TSn,
                                               const int* __restrict__ cand,
                                               int* __restrict__ topk) {
  __shared__ float tsrow[D];
  __shared__ double sval[16];
  __shared__ int    sidx[16];
  const int b = blockIdx.x, tid = threadIdx.x;
  const int lane = tid & 63, w = tid >> 6;
#pragma unroll
  for (int j = 0; j < 3; j++) tsrow[tid + 256 * j] = TSn[(size_t)b * D + tid + 256 * j];
  __syncthreads();
  for (int c = w; c < 16; c += 4) {
    int q = cand[b * 16 + c];
    const float* sr = SUPn + (size_t)q * D;
    double dot = 0.0;
#pragma unroll
    for (int i = 0; i < 12; i++)
      dot += (double)sr[lane + 64 * i] * (double)tsrow[lane + 64 * i];
#pragma unroll
    for (int m = 32; m; m >>= 1) dot += __shfl_xor(dot, m);
    if (lane == 0) { sval[c] = dot; sidx[c] = q; }
  }
  __syncthreads();
  if (tid == 0) {
    for (int i = 1; i < 16; i++) {
      double v = sval[i]; int ix = sidx[i];
      int j = i - 1;
      while (j >= 0 && (sval[j] < v || (sval[j] == v && sidx[j] > ix))) {
        sval[j + 1] = sval[j]; sidx[j + 1] = sidx[j]; j--;
      }
      sval[j + 1] = v; sidx[j + 1] = ix;
    }
#pragma unroll
    for (int k = 0; k < 8; k++) topk[b * 8 + k] = sidx[k];
  }
}

// ---------------- K6: gather rows to output + positive + pos_sim -----------
__global__ __launch_bounds__(256) void gather_pos(const float* __restrict__ SUPn,
                                                  const float* __restrict__ TSn,
                                                  const int* __restrict__ topk,
                                                  float* __restrict__ out,
                                                  double* __restrict__ pos_sim, int Q) {
  __shared__ int idx[8];
  __shared__ double red[4];
  const int b = blockIdx.x, tid = threadIdx.x;
  if (tid < 8) idx[tid] = topk[b * 8 + tid];
  __syncthreads();
  float mean[3] = {0.f, 0.f, 0.f};
#pragma unroll
  for (int k = 0; k < 8; k++) {
    const float* sr = SUPn + (size_t)idx[k] * D;
    float* orow = out + ((size_t)b * 8 + k) * D;
#pragma unroll
    for (int j = 0; j < 3; j++) {
      float x = sr[tid + 256 * j];
      orow[tid + 256 * j] = x;
      mean[j] += x;
    }
  }
#pragma unroll
  for (int j = 0; j < 3; j++) mean[j] *= 0.125f;
  double ss = 0.0;
#pragma unroll
  for (int j = 0; j < 3; j++) ss += (double)mean[j] * mean[j];
  ss = blk_sum(ss, red);
  double inv = 1.0 / fmax(sqrt(ss), 1e-12);
  double dot = 0.0;
#pragma unroll
  for (int j = 0; j < 3; j++)
    dot += (double)TSn[(size_t)b * D + tid + 256 * j] * ((double)mean[j] * inv);
  dot = blk_sum(dot, red);
  if (tid == 0) pos_sim[b] = dot / (double)0.07f;
}

// ---------------- K7: per-row NNCL logsumexp --------------------------------
__global__ __launch_bounds__(256) void nncl_rows(const float* __restrict__ TSn,
                                                 const double* __restrict__ pos_sim,
                                                 double* __restrict__ row_loss) {
  __shared__ float tsb[D];
  __shared__ double red[4];
  const int b = blockIdx.x, c = threadIdx.x;
#pragma unroll
  for (int j = 0; j < 3; j++) tsb[c + 256 * j] = TSn[(size_t)b * D + c + 256 * j];
  __syncthreads();
  const float* tc = TSn + (size_t)c * D;
  double dot = 0.0;
  for (int e = 0; e < D; e += 4) {
    float4 t4 = *(const float4*)(tc + e);
    dot += (double)tsb[e] * t4.x + (double)tsb[e + 1] * t4.y +
           (double)tsb[e + 2] * t4.z + (double)tsb[e + 3] * t4.w;
  }
  const bool diag = (c == b);
  double logit = dot / (double)0.07f;
  double p = pos_sim[b];
  double m = blk_max(diag ? -1e300 : logit, red);
  m = fmax(m, p);
  double term = diag ? 0.0 : exp(logit - m);
  double ssum = blk_sum(term, red);
  ssum += exp(p - m);
  if (c == 0) row_loss[b] = (log(ssum) + m) - p;
}

// ---------------- K8: finalize scalars --------------------------------------
__global__ __launch_bounds__(256) void finalize(const float* __restrict__ maxsim,
                                                const double* __restrict__ row_loss,
                                                float* __restrict__ d_out, int out_size,
                                                int V, int B) {
  __shared__ double red[4];
  const int tid = threadIdx.x;
  double s1 = 0.0;
  for (int v = tid; v < V; v += 256) s1 += 2.0 - 2.0 * (double)maxsim[v];
  s1 = blk_sum(s1, red);
  __syncthreads();
  double s2 = 0.0;
  for (int b = tid; b < B; b += 256) s2 += row_loss[b];
  s2 = blk_sum(s2, red);
  if (tid == 0) {
    d_out[out_size - 2] = (float)(s1 / ((double)V * (double)D));
    d_out[out_size - 1] = (float)(s2 / (double)B);
  }
}

// ---------------- host launcher ---------------------------------------------
extern "C" void kernel_launch(void* const* d_in, const int* in_sizes, int n_in,
                              void* d_out, int out_size, void* d_ws, size_t ws_size,
                              hipStream_t stream) {
  const float* TS  = (const float*)d_in[0];
  const float* W   = (const float*)d_in[1];
  const float* T   = (const float*)d_in[2];
  const float* SUP = (const float*)d_in[3];
  const int B = in_sizes[0] / D;   // 256
  const int V = in_sizes[1] / D;   // 50257
  const int U = in_sizes[2] / D;   // 1000
  const int Q = in_sizes[3] / D;   // 10000
  const int NT   = (U + 15) / 16;  // 63
  const int UPAD = NT * 16;        // 1008
  const int V128 = (V + 127) & ~127; // 50304
  const int QPAD = (Q + 63) & ~63; // 10048
  const int NTB  = B / 16;         // 16

  char* ws = (char*)d_ws;
  size_t off = 0;
  auto alloc = [&](size_t bytes) -> char* {
    char* p = ws + off;
    off = (off + bytes + 255) & ~(size_t)255;
    return p;
  };
  bf16_t* t_bf   = (bf16_t*)alloc((size_t)UPAD * D * 2);
  float*  maxsim = (float*) alloc((size_t)V128 * 4);
  float*  ts_n   = (float*) alloc((size_t)B * D * 4);
  bf16_t* ts_bf  = (bf16_t*)alloc((size_t)B * D * 2);
  float*  sup_n  = (float*) alloc((size_t)Q * D * 4);
  float*  simf   = (float*) alloc((size_t)B * QPAD * 4);
  int*    cand   = (int*)   alloc((size_t)B * 16 * 4);
  int*    tki    = (int*)   alloc((size_t)B * 8 * 4);
  double* psim   = (double*)alloc((size_t)B * 8);
  double* rloss  = (double*)alloc((size_t)B * 8);
  (void)ws_size; (void)n_in;

  norm_rows<<<UPAD / 4, 256, 0, stream>>>(T,   nullptr, t_bf,  U, UPAD);
  norm_rows<<<B    / 4, 256, 0, stream>>>(TS,  ts_n,  ts_bf,   B, B);
  norm_rows<<<(Q + 3) / 4, 256, 0, stream>>>(SUP, sup_n, nullptr, Q, Q);

  maxsim_gemm<<<V128 / 128, 256, 0, stream>>>(W, t_bf, maxsim, V, U, NT);

  simf_gemm<<<QPAD / 64, 256, 0, stream>>>(sup_n, ts_bf, simf, Q, QPAD, NTB);
  topk16_f32<<<B, 256, 0, stream>>>(simf, cand, Q, QPAD);
  rescore<<<B, 256, 0, stream>>>(sup_n, ts_n, cand, tki);

  gather_pos<<<B, 256, 0, stream>>>(sup_n, ts_n, tki, (float*)d_out, psim, Q);
  nncl_rows<<<B, 256, 0, stream>>>(ts_n, psim, rloss);
  finalize<<<1, 256, 0, stream>>>(maxsim, rloss, (float*)d_out, out_size, V, B);
}